// Round 3
// baseline (491.961 us; speedup 1.0000x reference)
//
#include <hip/hip_runtime.h>
#include <hip/hip_bf16.h>
#include <math.h>

#define B_ 4
#define T_ 2048
#define DM 768
#define H_ 12
#define DH 64

typedef __attribute__((ext_vector_type(4))) float f32x4;
typedef __attribute__((ext_vector_type(8))) short s16x8;

typedef const __attribute__((address_space(1))) void* gas1_t;
typedef __attribute__((address_space(3))) void* las3_t;

__device__ __forceinline__ ushort f2b(float f) {
  union { float f; unsigned u; } v; v.f = f;
  unsigned u = v.u;
  u += 0x7fffu + ((u >> 16) & 1u);
  return (ushort)(u >> 16);
}
__device__ __forceinline__ float b2f(ushort b) {
  union { unsigned u; float f; } v; v.u = ((unsigned)b) << 16;
  return v.f;
}
__device__ __forceinline__ unsigned fbits(float f) {
  union { float f; unsigned u; } v; v.f = f; return v.u;
}

// ---------------- fp32 -> bf16 conversion, 4 elems/thread ----------------
__global__ void cvt_bf16(const float* __restrict__ src, ushort* __restrict__ dst, int n4) {
  int i = blockIdx.x * blockDim.x + threadIdx.x;
  if (i >= n4) return;
  float4 v = ((const float4*)src)[i];
  ushort4 o;
  o.x = f2b(v.x); o.y = f2b(v.y); o.z = f2b(v.z); o.w = f2b(v.w);
  ((ushort4*)dst)[i] = o;
}

// fused conversion of the 4 weight matrices (each 768*768; n4 each = 147456)
__global__ void cvt_w(const float* __restrict__ wq, const float* __restrict__ wk,
                      const float* __restrict__ wv, const float* __restrict__ wo,
                      ushort* __restrict__ wqkv, ushort* __restrict__ wob) {
  int i = blockIdx.x * blockDim.x + threadIdx.x;  // 4*147456 threads
  int which = i / 147456, j = i - which * 147456;
  const float* src = which == 0 ? wq : which == 1 ? wk : which == 2 ? wv : wo;
  ushort* dst = which < 3 ? wqkv + (size_t)which * 589824 : wob;
  float4 v = ((const float4*)src)[j];
  ushort4 o;
  o.x = f2b(v.x); o.y = f2b(v.y); o.z = f2b(v.z); o.w = f2b(v.w);
  ((ushort4*)dst)[j] = o;
}

// ---------------- NT bf16 GEMM: C[M][N] = A[M][K] * Bw[N][K]^T ----------------
template <bool F32OUT>
__global__ __launch_bounds__(256) void gemm_bt(
    const ushort* __restrict__ A, const ushort* __restrict__ Bw,
    void* __restrict__ Cv, int M, int N, int K) {
  __shared__ ushort As[128 * 32];
  __shared__ ushort Bs[128 * 32];
  const int m0 = blockIdx.y * 128, n0 = blockIdx.x * 128;
  const int tid = threadIdx.x;
  const int wave = tid >> 6, lane = tid & 63;
  const int wm = (wave >> 1) * 64, wn = (wave & 1) * 64;
  const int quad = lane >> 4, l16 = lane & 15;
  const int tr = tid >> 2, tc = (tid & 3) * 8;

  f32x4 acc[4][4] = {};

  const ushort* ga = A + (size_t)(m0 + tr) * K + tc;
  const ushort* gb = Bw + (size_t)(n0 + tr) * K + tc;

  for (int k0 = 0; k0 < K; k0 += 32) {
    __builtin_amdgcn_global_load_lds((gas1_t)(ga + k0), (las3_t)(As + tid * 8), 16, 0, 0);
    __builtin_amdgcn_global_load_lds((gas1_t)(ga + (size_t)64 * K + k0), (las3_t)(As + 2048 + tid * 8), 16, 0, 0);
    __builtin_amdgcn_global_load_lds((gas1_t)(gb + k0), (las3_t)(Bs + tid * 8), 16, 0, 0);
    __builtin_amdgcn_global_load_lds((gas1_t)(gb + (size_t)64 * K + k0), (las3_t)(Bs + 2048 + tid * 8), 16, 0, 0);
    __syncthreads();
    s16x8 af[4], bf[4];
#pragma unroll
    for (int i = 0; i < 4; i++)
      af[i] = *(const s16x8*)(As + (wm + i * 16 + l16) * 32 + quad * 8);
#pragma unroll
    for (int n = 0; n < 4; n++)
      bf[n] = *(const s16x8*)(Bs + (wn + n * 16 + l16) * 32 + quad * 8);
#pragma unroll
    for (int i = 0; i < 4; i++)
#pragma unroll
      for (int n = 0; n < 4; n++)
        acc[i][n] = __builtin_amdgcn_mfma_f32_16x16x32_bf16(af[i], bf[n], acc[i][n], 0, 0, 0);
    __syncthreads();
  }

#pragma unroll
  for (int i = 0; i < 4; i++) {
    int row = m0 + wm + i * 16 + quad * 4;
#pragma unroll
    for (int n = 0; n < 4; n++) {
      int col = n0 + wn + n * 16 + l16;
#pragma unroll
      for (int r = 0; r < 4; r++) {
        if constexpr (F32OUT)
          ((float*)Cv)[(size_t)(row + r) * N + col] = acc[i][n][r];
        else
          ((ushort*)Cv)[(size_t)(row + r) * N + col] = f2b(acc[i][n][r]);
      }
    }
  }
}

// ---------------- RoPE on Q,K; scatter into [B,H,T,DH] bf16 ----------------
__global__ void rope_qk(const ushort* __restrict__ qkv,
                        const float* __restrict__ cs, const float* __restrict__ sn,
                        ushort* __restrict__ Qb, ushort* __restrict__ Kb) {
  int idx = blockIdx.x * blockDim.x + threadIdx.x;  // B*T*H*32
  int i = idx & 31;
  int h = (idx >> 5) % H_;
  int m = idx / (32 * H_);
  int t = m & (T_ - 1);
  int b = m >> 11;
  float c = cs[t * 32 + i], s = sn[t * 32 + i];
  const ushort* row = qkv + (size_t)m * 2304;
  size_t obase = (((size_t)(b * H_ + h)) * T_ + t) * DH + 2 * i;
  {
    unsigned p = *(const unsigned*)(row + h * 64 + 2 * i);
    float x1 = b2f((ushort)(p & 0xffff)), x2 = b2f((ushort)(p >> 16));
    unsigned r1 = f2b(x1 * c - x2 * s), r2 = f2b(x1 * s + x2 * c);
    *(unsigned*)(Qb + obase) = r1 | (r2 << 16);
  }
  {
    unsigned p = *(const unsigned*)(row + 768 + h * 64 + 2 * i);
    float x1 = b2f((ushort)(p & 0xffff)), x2 = b2f((ushort)(p >> 16));
    unsigned r1 = f2b(x1 * c - x2 * s), r2 = f2b(x1 * s + x2 * c);
    *(unsigned*)(Kb + obase) = r1 | (r2 << 16);
  }
}

// ---------------- V transpose: qkv v-part -> Vt [B,H,DH,T] bf16 ----------------
__global__ __launch_bounds__(256) void vtrans(const ushort* __restrict__ qkv, ushort* __restrict__ Vt) {
  __shared__ ushort tile[64][65];
  int t0 = blockIdx.x * 64, bh = blockIdx.y;
  int b = bh / H_, h = bh % H_;
  int tid = threadIdx.x;
#pragma unroll
  for (int j = 0; j < 8; j++) {
    int lin = tid + j * 256;
    int row = lin >> 5;
    int cu = lin & 31;
    unsigned v = *(const unsigned*)(qkv + (size_t)(b * T_ + t0 + row) * 2304 + 1536 + h * 64 + cu * 2);
    tile[row][cu * 2] = (ushort)(v & 0xffff);
    tile[row][cu * 2 + 1] = (ushort)(v >> 16);
  }
  __syncthreads();
#pragma unroll
  for (int j = 0; j < 8; j++) {
    int lin = tid + j * 256;
    int d = lin >> 5;
    int tcol = (lin & 31) * 2;
    unsigned v = (unsigned)tile[tcol][d] | ((unsigned)tile[tcol + 1][d] << 16);
    *(unsigned*)(Vt + ((size_t)(bh * 64 + d)) * T_ + t0 + tcol) = v;
  }
}

// ---------------- causal flash attention v3 ----------------
// 2-wave blocks; wave w handles q-slice 127-(2*bx+w) (16 rows). Slices 2j,2j+1
// always have equal kv-tile counts -> perfect balance. S^T = K*Q^T via operand
// swap so exp outputs are kv-consecutive: pack 2xf32->1 VGPR (v_perm) and
// write P with 4 ds_write_b64; PV reads 2 ds_read_b128. No barriers.
#define EXP2SCALE 0.18033688f   /* 0.125 * log2(e) */
#define EXP2OFF  17.312340f     /* 12 * log2(e) */
__global__ __launch_bounds__(128, 4) void attn(const ushort* __restrict__ Qb, const ushort* __restrict__ Kb,
                                               const ushort* __restrict__ Vt, ushort* __restrict__ Ob) {
  const int bh = blockIdx.y;
  const int tid = threadIdx.x, wave = tid >> 6, lane = tid & 63;
  const int quad = lane >> 4, l16 = lane & 15;
  const int slice = 127 - (blockIdx.x * 2 + wave);  // biggest work first
  const int qw = slice * 16;
  const int nkv = (slice >> 2) + 1;
  const int b = bh / H_, h = bh % H_;
  const ushort* Qp = Qb + (size_t)bh * T_ * DH;
  const ushort* Kp = Kb + (size_t)bh * T_ * DH;
  const ushort* Vp = Vt + (size_t)bh * DH * T_;
  __shared__ ushort P[2][16][72];  // per-wave, padded (row=q, col=kv)

  // Q fragments: B-operand of S^T mfma: lane needs Q[q=l16][d=quad*8+j]
  s16x8 aq0 = *(const s16x8*)(Qp + (size_t)(qw + l16) * DH + quad * 8);
  s16x8 aq1 = *(const s16x8*)(Qp + (size_t)(qw + l16) * DH + 32 + quad * 8);
  f32x4 o[4] = {};
  float rsum = 0.f;  // partial l for q = qw + l16 over this lane's kv slices

  for (int c = 0; c < nkv; c++) {
    const int kv0 = c * 64;
    // K fragments: A-operand: lane needs K[kv=kv0+nt*16+l16][d=quad*8+j]
    s16x8 kf0[4], kf1[4];
#pragma unroll
    for (int nt = 0; nt < 4; nt++) {
      const ushort* kp = Kp + (size_t)(kv0 + nt * 16 + l16) * DH + quad * 8;
      kf0[nt] = *(const s16x8*)kp;
      kf1[nt] = *(const s16x8*)(kp + 32);
    }
    // V fragments (B-operand of PV): lane needs V[kv=kv0+quad*8+j][d=dt*16+l16]
    s16x8 bv0[4], bv1[4];
#pragma unroll
    for (int dt = 0; dt < 4; dt++) {
      const ushort* vp = Vp + (size_t)(dt * 16 + l16) * T_ + kv0 + quad * 8;
      bv0[dt] = *(const s16x8*)vp;
      bv1[dt] = *(const s16x8*)(vp + 32);
    }
    // S^T[kv][q] = K · Q^T : C row = kv_local = quad*4+r, col = q = l16
    f32x4 st[4] = {};
#pragma unroll
    for (int nt = 0; nt < 4; nt++) {
      st[nt] = __builtin_amdgcn_mfma_f32_16x16x32_bf16(kf0[nt], aq0, st[nt], 0, 0, 0);
      st[nt] = __builtin_amdgcn_mfma_f32_16x16x32_bf16(kf1[nt], aq1, st[nt], 0, 0, 0);
    }
    if (c == nkv - 1) {
      // diagonal tile: causal mask kv <= q
      const int q = qw + l16;
#pragma unroll
      for (int nt = 0; nt < 4; nt++) {
        float p[4];
#pragma unroll
        for (int r = 0; r < 4; r++) {
          int kv = kv0 + nt * 16 + quad * 4 + r;
          p[r] = (kv <= q) ? __builtin_amdgcn_exp2f(fmaf(st[nt][r], EXP2SCALE, -EXP2OFF)) : 0.f;
          rsum += p[r];
        }
        uint2 pk;
        pk.x = __builtin_amdgcn_perm(fbits(p[1]) + 0x8000u, fbits(p[0]) + 0x8000u, 0x07060302u);
        pk.y = __builtin_amdgcn_perm(fbits(p[3]) + 0x8000u, fbits(p[2]) + 0x8000u, 0x07060302u);
        *(uint2*)&P[wave][l16][nt * 16 + quad * 4] = pk;
      }
    } else {
#pragma unroll
      for (int nt = 0; nt < 4; nt++) {
        float p[4];
#pragma unroll
        for (int r = 0; r < 4; r++) {
          p[r] = __builtin_amdgcn_exp2f(fmaf(st[nt][r], EXP2SCALE, -EXP2OFF));
          rsum += p[r];
        }
        uint2 pk;
        pk.x = __builtin_amdgcn_perm(fbits(p[1]) + 0x8000u, fbits(p[0]) + 0x8000u, 0x07060302u);
        pk.y = __builtin_amdgcn_perm(fbits(p[3]) + 0x8000u, fbits(p[2]) + 0x8000u, 0x07060302u);
        *(uint2*)&P[wave][l16][nt * 16 + quad * 4] = pk;
      }
    }
    // P A-fragments: lane needs P[q=l16][kv=32h+quad*8+j]
    s16x8 ap0 = *(const s16x8*)&P[wave][l16][quad * 8];
    s16x8 ap1 = *(const s16x8*)&P[wave][l16][32 + quad * 8];
#pragma unroll
    for (int dt = 0; dt < 4; dt++) {
      o[dt] = __builtin_amdgcn_mfma_f32_16x16x32_bf16(ap0, bv0[dt], o[dt], 0, 0, 0);
      o[dt] = __builtin_amdgcn_mfma_f32_16x16x32_bf16(ap1, bv1[dt], o[dt], 0, 0, 0);
    }
  }
  // total l for q = qw + l16 (sum across quads), then redistribute
  rsum += __shfl_xor(rsum, 16);
  rsum += __shfl_xor(rsum, 32);
  float rinv[4];
#pragma unroll
  for (int r = 0; r < 4; r++)
    rinv[r] = __builtin_amdgcn_rcpf(__shfl(rsum, quad * 4 + r));
#pragma unroll
  for (int dt = 0; dt < 4; dt++)
#pragma unroll
    for (int r = 0; r < 4; r++) {
      int q = qw + quad * 4 + r;
      Ob[(size_t)(b * T_ + q) * DM + h * 64 + dt * 16 + l16] = f2b(o[dt][r] * rinv[r]);
    }
}

extern "C" void kernel_launch(void* const* d_in, const int* in_sizes, int n_in,
                              void* d_out, int out_size, void* d_ws, size_t ws_size,
                              hipStream_t stream) {
  const float* x = (const float*)d_in[0];
  const float* rc = (const float*)d_in[1];
  const float* rs = (const float*)d_in[2];
  const float* wq = (const float*)d_in[3];
  const float* wk = (const float*)d_in[4];
  const float* wv = (const float*)d_in[5];
  const float* wo = (const float*)d_in[6];

  char* ws = (char*)d_ws;
  ushort* xb   = (ushort*)(ws);
  ushort* wqkv = (ushort*)(ws + 12582912);
  ushort* wob  = (ushort*)(ws + 16121856);
  ushort* Qb   = (ushort*)(ws + 17301504);
  ushort* Kb   = (ushort*)(ws + 29884416);
  ushort* Vt   = (ushort*)(ws + 42467328);
  ushort* qkv  = (ushort*)(ws + 55050240);
  ushort* Ob   = qkv;  // alias: qkv temp dead after rope+vtrans

  cvt_bf16<<<6144, 256, 0, stream>>>(x, xb, 8192 * 768 / 4);
  cvt_w<<<2304, 256, 0, stream>>>(wq, wk, wv, wo, wqkv, wob);

  gemm_bt<false><<<dim3(18, 64), 256, 0, stream>>>(xb, wqkv, (void*)qkv, 8192, 2304, 768);

  rope_qk<<<12288, 256, 0, stream>>>(qkv, rc, rs, Qb, Kb);
  vtrans<<<dim3(32, 48), 256, 0, stream>>>(qkv, Vt);

  attn<<<dim3(64, 48), 128, 0, stream>>>(Qb, Kb, Vt, Ob);

  gemm_bt<true><<<dim3(6, 64), 256, 0, stream>>>(Ob, wob, d_out, 8192, 768, 768);
}

// Round 4
// 382.383 us; speedup vs baseline: 1.2866x; 1.2866x over previous
//
#include <hip/hip_runtime.h>
#include <hip/hip_bf16.h>
#include <math.h>

#define B_ 4
#define T_ 2048
#define DM 768
#define H_ 12
#define DH 64

typedef __attribute__((ext_vector_type(4))) float f32x4;
typedef __attribute__((ext_vector_type(8))) short s16x8;

typedef const __attribute__((address_space(1))) void* gas1_t;
typedef __attribute__((address_space(3))) void* las3_t;

__device__ __forceinline__ ushort f2b(float f) {
  union { float f; unsigned u; } v; v.f = f;
  unsigned u = v.u;
  u += 0x7fffu + ((u >> 16) & 1u);
  return (ushort)(u >> 16);
}
__device__ __forceinline__ float b2f(ushort b) {
  union { unsigned u; float f; } v; v.u = ((unsigned)b) << 16;
  return v.f;
}

// ---------------- fp32 -> bf16 conversion, 4 elems/thread ----------------
__global__ void cvt_bf16(const float* __restrict__ src, ushort* __restrict__ dst, int n4) {
  int i = blockIdx.x * blockDim.x + threadIdx.x;
  if (i >= n4) return;
  float4 v = ((const float4*)src)[i];
  ushort4 o;
  o.x = f2b(v.x); o.y = f2b(v.y); o.z = f2b(v.z); o.w = f2b(v.w);
  ((ushort4*)dst)[i] = o;
}

// fused conversion of the 4 weight matrices (each 768*768; n4 each = 147456)
__global__ void cvt_w(const float* __restrict__ wq, const float* __restrict__ wk,
                      const float* __restrict__ wv, const float* __restrict__ wo,
                      ushort* __restrict__ wqkv, ushort* __restrict__ wob) {
  int i = blockIdx.x * blockDim.x + threadIdx.x;  // 4*147456 threads
  int which = i / 147456, j = i - which * 147456;
  const float* src = which == 0 ? wq : which == 1 ? wk : which == 2 ? wv : wo;
  ushort* dst = which < 3 ? wqkv + (size_t)which * 589824 : wob;
  float4 v = ((const float4*)src)[j];
  ushort4 o;
  o.x = f2b(v.x); o.y = f2b(v.y); o.z = f2b(v.z); o.w = f2b(v.w);
  ((ushort4*)dst)[j] = o;
}

// ---------------- NT bf16 GEMM: C[M][N] = A[M][K] * Bw[N][K]^T ----------------
template <bool F32OUT>
__global__ __launch_bounds__(256) void gemm_bt(
    const ushort* __restrict__ A, const ushort* __restrict__ Bw,
    void* __restrict__ Cv, int M, int N, int K) {
  __shared__ ushort As[128 * 32];
  __shared__ ushort Bs[128 * 32];
  const int m0 = blockIdx.y * 128, n0 = blockIdx.x * 128;
  const int tid = threadIdx.x;
  const int wave = tid >> 6, lane = tid & 63;
  const int wm = (wave >> 1) * 64, wn = (wave & 1) * 64;
  const int quad = lane >> 4, l16 = lane & 15;
  const int tr = tid >> 2, tc = (tid & 3) * 8;

  f32x4 acc[4][4] = {};

  const ushort* ga = A + (size_t)(m0 + tr) * K + tc;
  const ushort* gb = Bw + (size_t)(n0 + tr) * K + tc;

  for (int k0 = 0; k0 < K; k0 += 32) {
    __builtin_amdgcn_global_load_lds((gas1_t)(ga + k0), (las3_t)(As + tid * 8), 16, 0, 0);
    __builtin_amdgcn_global_load_lds((gas1_t)(ga + (size_t)64 * K + k0), (las3_t)(As + 2048 + tid * 8), 16, 0, 0);
    __builtin_amdgcn_global_load_lds((gas1_t)(gb + k0), (las3_t)(Bs + tid * 8), 16, 0, 0);
    __builtin_amdgcn_global_load_lds((gas1_t)(gb + (size_t)64 * K + k0), (las3_t)(Bs + 2048 + tid * 8), 16, 0, 0);
    __syncthreads();
    s16x8 af[4], bf[4];
#pragma unroll
    for (int i = 0; i < 4; i++)
      af[i] = *(const s16x8*)(As + (wm + i * 16 + l16) * 32 + quad * 8);
#pragma unroll
    for (int n = 0; n < 4; n++)
      bf[n] = *(const s16x8*)(Bs + (wn + n * 16 + l16) * 32 + quad * 8);
#pragma unroll
    for (int i = 0; i < 4; i++)
#pragma unroll
      for (int n = 0; n < 4; n++)
        acc[i][n] = __builtin_amdgcn_mfma_f32_16x16x32_bf16(af[i], bf[n], acc[i][n], 0, 0, 0);
    __syncthreads();
  }

#pragma unroll
  for (int i = 0; i < 4; i++) {
    int row = m0 + wm + i * 16 + quad * 4;
#pragma unroll
    for (int n = 0; n < 4; n++) {
      int col = n0 + wn + n * 16 + l16;
#pragma unroll
      for (int r = 0; r < 4; r++) {
        if constexpr (F32OUT)
          ((float*)Cv)[(size_t)(row + r) * N + col] = acc[i][n][r];
        else
          ((ushort*)Cv)[(size_t)(row + r) * N + col] = f2b(acc[i][n][r]);
      }
    }
  }
}

// ---------------- RoPE on Q,K; scatter into [B,H,T,DH] bf16 ----------------
__global__ void rope_qk(const ushort* __restrict__ qkv,
                        const float* __restrict__ cs, const float* __restrict__ sn,
                        ushort* __restrict__ Qb, ushort* __restrict__ Kb) {
  int idx = blockIdx.x * blockDim.x + threadIdx.x;  // B*T*H*32
  int i = idx & 31;
  int h = (idx >> 5) % H_;
  int m = idx / (32 * H_);
  int t = m & (T_ - 1);
  int b = m >> 11;
  float c = cs[t * 32 + i], s = sn[t * 32 + i];
  const ushort* row = qkv + (size_t)m * 2304;
  size_t obase = (((size_t)(b * H_ + h)) * T_ + t) * DH + 2 * i;
  {
    unsigned p = *(const unsigned*)(row + h * 64 + 2 * i);
    float x1 = b2f((ushort)(p & 0xffff)), x2 = b2f((ushort)(p >> 16));
    unsigned r1 = f2b(x1 * c - x2 * s), r2 = f2b(x1 * s + x2 * c);
    *(unsigned*)(Qb + obase) = r1 | (r2 << 16);
  }
  {
    unsigned p = *(const unsigned*)(row + 768 + h * 64 + 2 * i);
    float x1 = b2f((ushort)(p & 0xffff)), x2 = b2f((ushort)(p >> 16));
    unsigned r1 = f2b(x1 * c - x2 * s), r2 = f2b(x1 * s + x2 * c);
    *(unsigned*)(Kb + obase) = r1 | (r2 << 16);
  }
}

// ---------------- V transpose: qkv v-part -> Vt [B,H,DH,T] bf16 ----------------
__global__ __launch_bounds__(256) void vtrans(const ushort* __restrict__ qkv, ushort* __restrict__ Vt) {
  __shared__ ushort tile[64][65];
  int t0 = blockIdx.x * 64, bh = blockIdx.y;
  int b = bh / H_, h = bh % H_;
  int tid = threadIdx.x;
#pragma unroll
  for (int j = 0; j < 8; j++) {
    int lin = tid + j * 256;
    int row = lin >> 5;
    int cu = lin & 31;
    unsigned v = *(const unsigned*)(qkv + (size_t)(b * T_ + t0 + row) * 2304 + 1536 + h * 64 + cu * 2);
    tile[row][cu * 2] = (ushort)(v & 0xffff);
    tile[row][cu * 2 + 1] = (ushort)(v >> 16);
  }
  __syncthreads();
#pragma unroll
  for (int j = 0; j < 8; j++) {
    int lin = tid + j * 256;
    int d = lin >> 5;
    int tcol = (lin & 31) * 2;
    unsigned v = (unsigned)tile[tcol][d] | ((unsigned)tile[tcol + 1][d] << 16);
    *(unsigned*)(Vt + ((size_t)(bh * 64 + d)) * T_ + t0 + tcol) = v;
  }
}

// ---------------- causal flash attention v4 (R2 structure, de-paired) ----------------
// grid (48 bh, 32 qt-desc). One 64-row q-tile per block, 4 waves, wave w owns
// 16 q rows. Register K-prefetch + early V issue hide global latency; P buffer
// wave-private (no barriers); fixed-max softmax (max=12), one l-reduce at end.
#define EXP2SCALE 0.18033688f   /* 0.125 * log2(e) */
#define EXP2OFF  17.312340f     /* 12 * log2(e) */
__global__ __launch_bounds__(256, 3) void attn(const ushort* __restrict__ Qb, const ushort* __restrict__ Kb,
                                               const ushort* __restrict__ Vt, ushort* __restrict__ Ob) {
  const int bh = blockIdx.x;
  const int qt = 31 - blockIdx.y;  // biggest tiles dispatch first
  const int tid = threadIdx.x, wave = tid >> 6, lane = tid & 63;
  const int quad = lane >> 4, l16 = lane & 15;
  const int b = bh / H_, h = bh % H_;
  const ushort* Qp = Qb + (size_t)bh * T_ * DH;
  const ushort* Kp = Kb + (size_t)bh * T_ * DH;
  const ushort* Vp = Vt + (size_t)bh * DH * T_;
  __shared__ ushort P[4][16][72];  // per-wave, padded

  const int qw = qt * 64 + wave * 16;

  s16x8 aq0 = *(const s16x8*)(Qp + (size_t)(qw + l16) * DH + quad * 8);
  s16x8 aq1 = *(const s16x8*)(Qp + (size_t)(qw + l16) * DH + 32 + quad * 8);
  f32x4 o[4] = {};
  float rsum[4] = {0.f, 0.f, 0.f, 0.f};

  s16x8 kf[4][2], kn[4][2];
#pragma unroll
  for (int nt = 0; nt < 4; nt++) {
    const ushort* kp = Kp + (size_t)(nt * 16 + l16) * DH + quad * 8;
    kf[nt][0] = *(const s16x8*)kp;
    kf[nt][1] = *(const s16x8*)(kp + 32);
  }

  for (int c = 0; c <= qt; c++) {
    const int kv0 = c * 64;
    f32x4 s[4] = {};
#pragma unroll
    for (int nt = 0; nt < 4; nt++) {
      s[nt] = __builtin_amdgcn_mfma_f32_16x16x32_bf16(aq0, kf[nt][0], s[nt], 0, 0, 0);
      s[nt] = __builtin_amdgcn_mfma_f32_16x16x32_bf16(aq1, kf[nt][1], s[nt], 0, 0, 0);
    }
    if (c < qt) {  // prefetch next K tile
#pragma unroll
      for (int nt = 0; nt < 4; nt++) {
        const ushort* kp = Kp + (size_t)(kv0 + 64 + nt * 16 + l16) * DH + quad * 8;
        kn[nt][0] = *(const s16x8*)kp;
        kn[nt][1] = *(const s16x8*)(kp + 32);
      }
    }
    // V loads issued before softmax so latency overlaps exp/LDS work
    s16x8 bv[4][2];
#pragma unroll
    for (int dt = 0; dt < 4; dt++) {
      const ushort* vp = Vp + (size_t)(dt * 16 + l16) * T_ + kv0 + quad * 8;
      bv[dt][0] = *(const s16x8*)vp;
      bv[dt][1] = *(const s16x8*)(vp + 32);
    }
    if (c < qt) {
#pragma unroll
      for (int nt = 0; nt < 4; nt++)
#pragma unroll
        for (int r = 0; r < 4; r++) {
          float p = __builtin_amdgcn_exp2f(fmaf(s[nt][r], EXP2SCALE, -EXP2OFF));
          rsum[r] += p;
          P[wave][quad * 4 + r][nt * 16 + l16] = f2b(p);
        }
    } else {  // diagonal tile: causal mask
#pragma unroll
      for (int nt = 0; nt < 4; nt++) {
        int kv = kv0 + nt * 16 + l16;
#pragma unroll
        for (int r = 0; r < 4; r++) {
          int qi = qw + quad * 4 + r;
          float p = (kv <= qi) ? __builtin_amdgcn_exp2f(fmaf(s[nt][r], EXP2SCALE, -EXP2OFF)) : 0.f;
          rsum[r] += p;
          P[wave][quad * 4 + r][nt * 16 + l16] = f2b(p);
        }
      }
    }
    s16x8 ap0 = *(const s16x8*)&P[wave][l16][quad * 8];
    s16x8 ap1 = *(const s16x8*)&P[wave][l16][32 + quad * 8];
#pragma unroll
    for (int dt = 0; dt < 4; dt++) {
      o[dt] = __builtin_amdgcn_mfma_f32_16x16x32_bf16(ap0, bv[dt][0], o[dt], 0, 0, 0);
      o[dt] = __builtin_amdgcn_mfma_f32_16x16x32_bf16(ap1, bv[dt][1], o[dt], 0, 0, 0);
    }
    if (c < qt) {
#pragma unroll
      for (int nt = 0; nt < 4; nt++) {
        kf[nt][0] = kn[nt][0];
        kf[nt][1] = kn[nt][1];
      }
    }
  }
  // one-time l reduction across the 16 kv-lanes
#pragma unroll
  for (int off = 1; off < 16; off <<= 1)
#pragma unroll
    for (int r = 0; r < 4; r++)
      rsum[r] += __shfl_xor(rsum[r], off);
#pragma unroll
  for (int dt = 0; dt < 4; dt++)
#pragma unroll
    for (int r = 0; r < 4; r++) {
      int q = qw + quad * 4 + r;
      Ob[(size_t)(b * T_ + q) * DM + h * 64 + dt * 16 + l16] = f2b(o[dt][r] / rsum[r]);
    }
}

extern "C" void kernel_launch(void* const* d_in, const int* in_sizes, int n_in,
                              void* d_out, int out_size, void* d_ws, size_t ws_size,
                              hipStream_t stream) {
  const float* x = (const float*)d_in[0];
  const float* rc = (const float*)d_in[1];
  const float* rs = (const float*)d_in[2];
  const float* wq = (const float*)d_in[3];
  const float* wk = (const float*)d_in[4];
  const float* wv = (const float*)d_in[5];
  const float* wo = (const float*)d_in[6];

  char* ws = (char*)d_ws;
  ushort* xb   = (ushort*)(ws);
  ushort* wqkv = (ushort*)(ws + 12582912);
  ushort* wob  = (ushort*)(ws + 16121856);
  ushort* Qb   = (ushort*)(ws + 17301504);
  ushort* Kb   = (ushort*)(ws + 29884416);
  ushort* Vt   = (ushort*)(ws + 42467328);
  ushort* qkv  = (ushort*)(ws + 55050240);
  ushort* Ob   = qkv;  // alias: qkv temp dead after rope+vtrans

  cvt_bf16<<<6144, 256, 0, stream>>>(x, xb, 8192 * 768 / 4);
  cvt_w<<<2304, 256, 0, stream>>>(wq, wk, wv, wo, wqkv, wob);

  gemm_bt<false><<<dim3(18, 64), 256, 0, stream>>>(xb, wqkv, (void*)qkv, 8192, 2304, 768);

  rope_qk<<<12288, 256, 0, stream>>>(qkv, rc, rs, Qb, Kb);
  vtrans<<<dim3(32, 48), 256, 0, stream>>>(qkv, Vt);

  attn<<<dim3(48, 32), 256, 0, stream>>>(Qb, Kb, Vt, Ob);

  gemm_bt<true><<<dim3(6, 64), 256, 0, stream>>>(Ob, wob, d_out, 8192, 768, 768);
}

// Round 5
// 237.157 us; speedup vs baseline: 2.0744x; 1.6124x over previous
//
#include <hip/hip_runtime.h>
#include <hip/hip_bf16.h>
#include <math.h>

#define B_ 4
#define T_ 2048
#define DM 768
#define H_ 12
#define DH 64

typedef __attribute__((ext_vector_type(4))) float f32x4;
typedef __attribute__((ext_vector_type(8))) short s16x8;

typedef const __attribute__((address_space(1))) void* gas1_t;
typedef __attribute__((address_space(3))) void* las3_t;

__device__ __forceinline__ ushort f2b(float f) {
  union { float f; unsigned u; } v; v.f = f;
  unsigned u = v.u;
  u += 0x7fffu + ((u >> 16) & 1u);
  return (ushort)(u >> 16);
}
__device__ __forceinline__ float b2f(ushort b) {
  union { unsigned u; float f; } v; v.u = ((unsigned)b) << 16;
  return v.f;
}

// ---------------- fp32 -> bf16 conversion, 4 elems/thread ----------------
__global__ void cvt_bf16(const float* __restrict__ src, ushort* __restrict__ dst, int n4) {
  int i = blockIdx.x * blockDim.x + threadIdx.x;
  if (i >= n4) return;
  float4 v = ((const float4*)src)[i];
  ushort4 o;
  o.x = f2b(v.x); o.y = f2b(v.y); o.z = f2b(v.z); o.w = f2b(v.w);
  ((ushort4*)dst)[i] = o;
}

// fused conversion of the 4 weight matrices (each 768*768; n4 each = 147456)
__global__ void cvt_w(const float* __restrict__ wq, const float* __restrict__ wk,
                      const float* __restrict__ wv, const float* __restrict__ wo,
                      ushort* __restrict__ wqkv, ushort* __restrict__ wob) {
  int i = blockIdx.x * blockDim.x + threadIdx.x;  // 4*147456 threads
  int which = i / 147456, j = i - which * 147456;
  const float* src = which == 0 ? wq : which == 1 ? wk : which == 2 ? wv : wo;
  ushort* dst = which < 3 ? wqkv + (size_t)which * 589824 : wob;
  float4 v = ((const float4*)src)[j];
  ushort4 o;
  o.x = f2b(v.x); o.y = f2b(v.y); o.z = f2b(v.z); o.w = f2b(v.w);
  ((ushort4*)dst)[j] = o;
}

// ---------------- NT bf16 GEMM: C[M][N] = A[M][K] * Bw[N][K]^T ----------------
template <bool F32OUT>
__global__ __launch_bounds__(256) void gemm_bt(
    const ushort* __restrict__ A, const ushort* __restrict__ Bw,
    void* __restrict__ Cv, int M, int N, int K) {
  __shared__ ushort As[128 * 32];
  __shared__ ushort Bs[128 * 32];
  const int m0 = blockIdx.y * 128, n0 = blockIdx.x * 128;
  const int tid = threadIdx.x;
  const int wave = tid >> 6, lane = tid & 63;
  const int wm = (wave >> 1) * 64, wn = (wave & 1) * 64;
  const int quad = lane >> 4, l16 = lane & 15;
  const int tr = tid >> 2, tc = (tid & 3) * 8;

  f32x4 acc[4][4] = {};

  const ushort* ga = A + (size_t)(m0 + tr) * K + tc;
  const ushort* gb = Bw + (size_t)(n0 + tr) * K + tc;

  for (int k0 = 0; k0 < K; k0 += 32) {
    __builtin_amdgcn_global_load_lds((gas1_t)(ga + k0), (las3_t)(As + tid * 8), 16, 0, 0);
    __builtin_amdgcn_global_load_lds((gas1_t)(ga + (size_t)64 * K + k0), (las3_t)(As + 2048 + tid * 8), 16, 0, 0);
    __builtin_amdgcn_global_load_lds((gas1_t)(gb + k0), (las3_t)(Bs + tid * 8), 16, 0, 0);
    __builtin_amdgcn_global_load_lds((gas1_t)(gb + (size_t)64 * K + k0), (las3_t)(Bs + 2048 + tid * 8), 16, 0, 0);
    __syncthreads();
    s16x8 af[4], bf[4];
#pragma unroll
    for (int i = 0; i < 4; i++)
      af[i] = *(const s16x8*)(As + (wm + i * 16 + l16) * 32 + quad * 8);
#pragma unroll
    for (int n = 0; n < 4; n++)
      bf[n] = *(const s16x8*)(Bs + (wn + n * 16 + l16) * 32 + quad * 8);
#pragma unroll
    for (int i = 0; i < 4; i++)
#pragma unroll
      for (int n = 0; n < 4; n++)
        acc[i][n] = __builtin_amdgcn_mfma_f32_16x16x32_bf16(af[i], bf[n], acc[i][n], 0, 0, 0);
    __syncthreads();
  }

#pragma unroll
  for (int i = 0; i < 4; i++) {
    int row = m0 + wm + i * 16 + quad * 4;
#pragma unroll
    for (int n = 0; n < 4; n++) {
      int col = n0 + wn + n * 16 + l16;
#pragma unroll
      for (int r = 0; r < 4; r++) {
        if constexpr (F32OUT)
          ((float*)Cv)[(size_t)(row + r) * N + col] = acc[i][n][r];
        else
          ((ushort*)Cv)[(size_t)(row + r) * N + col] = f2b(acc[i][n][r]);
      }
    }
  }
}

// ---------------- RoPE on Q,K; scatter into [B,H,T,DH] bf16 ----------------
__global__ void rope_qk(const ushort* __restrict__ qkv,
                        const float* __restrict__ cs, const float* __restrict__ sn,
                        ushort* __restrict__ Qb, ushort* __restrict__ Kb) {
  int idx = blockIdx.x * blockDim.x + threadIdx.x;  // B*T*H*32
  int i = idx & 31;
  int h = (idx >> 5) % H_;
  int m = idx / (32 * H_);
  int t = m & (T_ - 1);
  int b = m >> 11;
  float c = cs[t * 32 + i], s = sn[t * 32 + i];
  const ushort* row = qkv + (size_t)m * 2304;
  size_t obase = (((size_t)(b * H_ + h)) * T_ + t) * DH + 2 * i;
  {
    unsigned p = *(const unsigned*)(row + h * 64 + 2 * i);
    float x1 = b2f((ushort)(p & 0xffff)), x2 = b2f((ushort)(p >> 16));
    unsigned r1 = f2b(x1 * c - x2 * s), r2 = f2b(x1 * s + x2 * c);
    *(unsigned*)(Qb + obase) = r1 | (r2 << 16);
  }
  {
    unsigned p = *(const unsigned*)(row + 768 + h * 64 + 2 * i);
    float x1 = b2f((ushort)(p & 0xffff)), x2 = b2f((ushort)(p >> 16));
    unsigned r1 = f2b(x1 * c - x2 * s), r2 = f2b(x1 * s + x2 * c);
    *(unsigned*)(Kb + obase) = r1 | (r2 << 16);
  }
}

// ---------------- V transpose: qkv v-part -> Vt [B,H,DH,T] bf16 ----------------
__global__ __launch_bounds__(256) void vtrans(const ushort* __restrict__ qkv, ushort* __restrict__ Vt) {
  __shared__ ushort tile[64][65];
  int t0 = blockIdx.x * 64, bh = blockIdx.y;
  int b = bh / H_, h = bh % H_;
  int tid = threadIdx.x;
#pragma unroll
  for (int j = 0; j < 8; j++) {
    int lin = tid + j * 256;
    int row = lin >> 5;
    int cu = lin & 31;
    unsigned v = *(const unsigned*)(qkv + (size_t)(b * T_ + t0 + row) * 2304 + 1536 + h * 64 + cu * 2);
    tile[row][cu * 2] = (ushort)(v & 0xffff);
    tile[row][cu * 2 + 1] = (ushort)(v >> 16);
  }
  __syncthreads();
#pragma unroll
  for (int j = 0; j < 8; j++) {
    int lin = tid + j * 256;
    int d = lin >> 5;
    int tcol = (lin & 31) * 2;
    unsigned v = (unsigned)tile[tcol][d] | ((unsigned)tile[tcol + 1][d] << 16);
    *(unsigned*)(Vt + ((size_t)(bh * 64 + d)) * T_ + t0 + tcol) = v;
  }
}

// ---------------- causal flash attention v5: LDS-staged K/V, 128 q-rows/block ----------------
// grid (48 bh, 16 qt128-desc). 4 waves; wave w owns q rows qt*128+w*32..+31 as
// two 16-row m-frags. Per kv tile: K,V staged once to LDS (global_load_lds,
// XOR-swizzled source colblocks so frag reads are bank-conflict-free), shared
// by all 8 frag-streams -> 8x less L2/LLC traffic than v4. Fixed-max softmax.
#define EXP2SCALE 0.18033688f   /* 0.125 * log2(e) */
#define EXP2OFF  17.312340f     /* 12 * log2(e) */
__global__ __launch_bounds__(256, 3) void attn(const ushort* __restrict__ Qb, const ushort* __restrict__ Kb,
                                               const ushort* __restrict__ Vt, ushort* __restrict__ Ob) {
  const int bh = blockIdx.x;
  const int qt = 15 - blockIdx.y;  // biggest tiles dispatch first
  const int tid = threadIdx.x, wave = tid >> 6, lane = tid & 63;
  const int quad = lane >> 4, l16 = lane & 15;
  const int b = bh / H_, h = bh % H_;
  const ushort* Qp = Qb + (size_t)bh * T_ * DH;
  const ushort* Kp = Kb + (size_t)bh * T_ * DH;
  const ushort* Vp = Vt + (size_t)bh * DH * T_;

  __shared__ ushort Ks[64 * 64];        // [kvrow][cb] = K[kvrow][cb ^ (kvrow&7)]
  __shared__ ushort Vs[64 * 64];        // [d][cb]    = V[d][cb ^ (d&7)]
  __shared__ ushort P[4][2][16][72];    // per wave, per m-frag, padded

  const int qbase0 = qt * 128 + wave * 32;

  // Q fragments (A-operand): lane holds Q[q=base+l16][k=half*32+quad*8+j]
  s16x8 aq[2][2];
#pragma unroll
  for (int m = 0; m < 2; m++) {
    const ushort* qp = Qp + (size_t)(qbase0 + m * 16 + l16) * DH + quad * 8;
    aq[m][0] = *(const s16x8*)qp;
    aq[m][1] = *(const s16x8*)(qp + 32);
  }
  f32x4 o[2][4] = {};
  float rsum[2][4] = {{0.f, 0.f, 0.f, 0.f}, {0.f, 0.f, 0.f, 0.f}};

  const int ntile = 2 * qt + 2;
  const int srow = tid >> 3;                       // 0..31
  const int scbK = (tid & 7) ^ (srow & 7);         // swizzled source colblock
  const int swz = (l16 & 7);                       // read-side swizzle term

  for (int c = 0; c < ntile; c++) {
    const int kv0 = c * 64;
    __syncthreads();  // previous tile's LDS reads complete before overwrite
    __builtin_amdgcn_global_load_lds((gas1_t)(Kp + (size_t)(kv0 + srow) * DH + scbK * 8),
                                     (las3_t)(Ks + tid * 8), 16, 0, 0);
    __builtin_amdgcn_global_load_lds((gas1_t)(Kp + (size_t)(kv0 + srow + 32) * DH + scbK * 8),
                                     (las3_t)(Ks + 2048 + tid * 8), 16, 0, 0);
    __builtin_amdgcn_global_load_lds((gas1_t)(Vp + (size_t)srow * T_ + kv0 + scbK * 8),
                                     (las3_t)(Vs + tid * 8), 16, 0, 0);
    __builtin_amdgcn_global_load_lds((gas1_t)(Vp + (size_t)(srow + 32) * T_ + kv0 + scbK * 8),
                                     (las3_t)(Vs + 2048 + tid * 8), 16, 0, 0);
    __syncthreads();  // staging complete

    // K fragments (B-operand of QK): K[kv=nt*16+l16][k=half*32+quad*8+j]
    s16x8 kf[4][2];
#pragma unroll
    for (int nt = 0; nt < 4; nt++) {
      const ushort* kr = Ks + (nt * 16 + l16) * 64;
      kf[nt][0] = *(const s16x8*)(kr + ((quad ^ swz) * 8));
      kf[nt][1] = *(const s16x8*)(kr + (((4 + quad) ^ swz) * 8));
    }
    // V fragments (B-operand of PV): V[kv=half*32+quad*8+j][d=dt*16+l16]
    s16x8 bv[4][2];
#pragma unroll
    for (int dt = 0; dt < 4; dt++) {
      const ushort* vr = Vs + (dt * 16 + l16) * 64;
      bv[dt][0] = *(const s16x8*)(vr + ((quad ^ swz) * 8));
      bv[dt][1] = *(const s16x8*)(vr + (((4 + quad) ^ swz) * 8));
    }

#pragma unroll
    for (int m = 0; m < 2; m++) {
      const int qb = qbase0 + m * 16;
      if (kv0 > qb + 15) continue;  // fully masked frag (wave-uniform branch)
      f32x4 s[4] = {};
#pragma unroll
      for (int nt = 0; nt < 4; nt++) {
        s[nt] = __builtin_amdgcn_mfma_f32_16x16x32_bf16(aq[m][0], kf[nt][0], s[nt], 0, 0, 0);
        s[nt] = __builtin_amdgcn_mfma_f32_16x16x32_bf16(aq[m][1], kf[nt][1], s[nt], 0, 0, 0);
      }
      if (kv0 + 63 <= qb) {  // fully unmasked
#pragma unroll
        for (int nt = 0; nt < 4; nt++)
#pragma unroll
          for (int r = 0; r < 4; r++) {
            float p = __builtin_amdgcn_exp2f(fmaf(s[nt][r], EXP2SCALE, -EXP2OFF));
            rsum[m][r] += p;
            P[wave][m][quad * 4 + r][nt * 16 + l16] = f2b(p);
          }
      } else {  // diagonal tile
#pragma unroll
        for (int nt = 0; nt < 4; nt++) {
          int kv = kv0 + nt * 16 + l16;
#pragma unroll
          for (int r = 0; r < 4; r++) {
            int qi = qb + quad * 4 + r;
            float p = (kv <= qi) ? __builtin_amdgcn_exp2f(fmaf(s[nt][r], EXP2SCALE, -EXP2OFF)) : 0.f;
            rsum[m][r] += p;
            P[wave][m][quad * 4 + r][nt * 16 + l16] = f2b(p);
          }
        }
      }
      s16x8 ap0 = *(const s16x8*)&P[wave][m][l16][quad * 8];
      s16x8 ap1 = *(const s16x8*)&P[wave][m][l16][32 + quad * 8];
#pragma unroll
      for (int dt = 0; dt < 4; dt++) {
        o[m][dt] = __builtin_amdgcn_mfma_f32_16x16x32_bf16(ap0, bv[dt][0], o[m][dt], 0, 0, 0);
        o[m][dt] = __builtin_amdgcn_mfma_f32_16x16x32_bf16(ap1, bv[dt][1], o[m][dt], 0, 0, 0);
      }
    }
  }
  // l reduction across the 16 kv-lanes, then write
#pragma unroll
  for (int off = 1; off < 16; off <<= 1)
#pragma unroll
    for (int m = 0; m < 2; m++)
#pragma unroll
      for (int r = 0; r < 4; r++)
        rsum[m][r] += __shfl_xor(rsum[m][r], off);
#pragma unroll
  for (int m = 0; m < 2; m++)
#pragma unroll
    for (int dt = 0; dt < 4; dt++)
#pragma unroll
      for (int r = 0; r < 4; r++) {
        int q = qbase0 + m * 16 + quad * 4 + r;
        Ob[(size_t)(b * T_ + q) * DM + h * 64 + dt * 16 + l16] = f2b(o[m][dt][r] / rsum[m][r]);
      }
}

extern "C" void kernel_launch(void* const* d_in, const int* in_sizes, int n_in,
                              void* d_out, int out_size, void* d_ws, size_t ws_size,
                              hipStream_t stream) {
  const float* x = (const float*)d_in[0];
  const float* rc = (const float*)d_in[1];
  const float* rs = (const float*)d_in[2];
  const float* wq = (const float*)d_in[3];
  const float* wk = (const float*)d_in[4];
  const float* wv = (const float*)d_in[5];
  const float* wo = (const float*)d_in[6];

  char* ws = (char*)d_ws;
  ushort* xb   = (ushort*)(ws);
  ushort* wqkv = (ushort*)(ws + 12582912);
  ushort* wob  = (ushort*)(ws + 16121856);
  ushort* Qb   = (ushort*)(ws + 17301504);
  ushort* Kb   = (ushort*)(ws + 29884416);
  ushort* Vt   = (ushort*)(ws + 42467328);
  ushort* qkv  = (ushort*)(ws + 55050240);
  ushort* Ob   = qkv;  // alias: qkv temp dead after rope+vtrans

  cvt_bf16<<<6144, 256, 0, stream>>>(x, xb, 8192 * 768 / 4);
  cvt_w<<<2304, 256, 0, stream>>>(wq, wk, wv, wo, wqkv, wob);

  gemm_bt<false><<<dim3(18, 64), 256, 0, stream>>>(xb, wqkv, (void*)qkv, 8192, 2304, 768);

  rope_qk<<<12288, 256, 0, stream>>>(qkv, rc, rs, Qb, Kb);
  vtrans<<<dim3(32, 48), 256, 0, stream>>>(qkv, Vt);

  attn<<<dim3(48, 16), 256, 0, stream>>>(Qb, Kb, Vt, Ob);

  gemm_bt<true><<<dim3(6, 64), 256, 0, stream>>>(Ob, wob, d_out, 8192, 768, 768);
}

// Round 6
// 231.339 us; speedup vs baseline: 2.1266x; 1.0251x over previous
//
#include <hip/hip_runtime.h>
#include <hip/hip_bf16.h>
#include <math.h>

#define B_ 4
#define T_ 2048
#define DM 768
#define H_ 12
#define DH 64

typedef __attribute__((ext_vector_type(4))) float f32x4;
typedef __attribute__((ext_vector_type(8))) short s16x8;

typedef const __attribute__((address_space(1))) void* gas1_t;
typedef __attribute__((address_space(3))) void* las3_t;

__device__ __forceinline__ ushort f2b(float f) {
  union { float f; unsigned u; } v; v.f = f;
  unsigned u = v.u;
  u += 0x7fffu + ((u >> 16) & 1u);
  return (ushort)(u >> 16);
}
__device__ __forceinline__ float b2f(ushort b) {
  union { unsigned u; float f; } v; v.u = ((unsigned)b) << 16;
  return v.f;
}

// ---------------- fp32 -> bf16 conversion, 4 elems/thread ----------------
__global__ void cvt_bf16(const float* __restrict__ src, ushort* __restrict__ dst, int n4) {
  int i = blockIdx.x * blockDim.x + threadIdx.x;
  if (i >= n4) return;
  float4 v = ((const float4*)src)[i];
  ushort4 o;
  o.x = f2b(v.x); o.y = f2b(v.y); o.z = f2b(v.z); o.w = f2b(v.w);
  ((ushort4*)dst)[i] = o;
}

// fused conversion of the 4 weight matrices (each 768*768; n4 each = 147456)
__global__ void cvt_w(const float* __restrict__ wq, const float* __restrict__ wk,
                      const float* __restrict__ wv, const float* __restrict__ wo,
                      ushort* __restrict__ wqkv, ushort* __restrict__ wob) {
  int i = blockIdx.x * blockDim.x + threadIdx.x;  // 4*147456 threads
  int which = i / 147456, j = i - which * 147456;
  const float* src = which == 0 ? wq : which == 1 ? wk : which == 2 ? wv : wo;
  ushort* dst = which < 3 ? wqkv + (size_t)which * 589824 : wob;
  float4 v = ((const float4*)src)[j];
  ushort4 o;
  o.x = f2b(v.x); o.y = f2b(v.y); o.z = f2b(v.z); o.w = f2b(v.w);
  ((ushort4*)dst)[j] = o;
}

// pack cos/sin tables into float2 [t][i]
__global__ void pack_cs(const float* __restrict__ cs, const float* __restrict__ sn,
                        float2* __restrict__ cs2, int n) {
  int i = blockIdx.x * blockDim.x + threadIdx.x;
  if (i < n) cs2[i] = make_float2(cs[i], sn[i]);
}

// ---------------- QKV GEMM with fused RoPE + scatter epilogue ----------------
// C-tile n-range lies entirely in one of {q,k,v} (768%128==0). q/k: RoPE via
// lane-pair shfl (adjacent col = adjacent lane), scatter to [bh][t][64]. v:
// transpose-scatter to Vt [bh][d][T] (4 t's per lane -> one b64 store).
__global__ __launch_bounds__(256) void gemm_qkv(
    const ushort* __restrict__ A, const ushort* __restrict__ Bw,
    const float2* __restrict__ cs2,
    ushort* __restrict__ Qb, ushort* __restrict__ Kb, ushort* __restrict__ Vt) {
  const int K = 768;
  __shared__ ushort As[128 * 32];
  __shared__ ushort Bs[128 * 32];
  const int m0 = blockIdx.y * 128, n0 = blockIdx.x * 128;
  const int tid = threadIdx.x;
  const int wave = tid >> 6, lane = tid & 63;
  const int wm = (wave >> 1) * 64, wn = (wave & 1) * 64;
  const int quad = lane >> 4, l16 = lane & 15;
  const int tr = tid >> 2, tc = (tid & 3) * 8;

  f32x4 acc[4][4] = {};

  const ushort* ga = A + (size_t)(m0 + tr) * K + tc;
  const ushort* gb = Bw + (size_t)(n0 + tr) * K + tc;

  for (int k0 = 0; k0 < K; k0 += 32) {
    __builtin_amdgcn_global_load_lds((gas1_t)(ga + k0), (las3_t)(As + tid * 8), 16, 0, 0);
    __builtin_amdgcn_global_load_lds((gas1_t)(ga + (size_t)64 * K + k0), (las3_t)(As + 2048 + tid * 8), 16, 0, 0);
    __builtin_amdgcn_global_load_lds((gas1_t)(gb + k0), (las3_t)(Bs + tid * 8), 16, 0, 0);
    __builtin_amdgcn_global_load_lds((gas1_t)(gb + (size_t)64 * K + k0), (las3_t)(Bs + 2048 + tid * 8), 16, 0, 0);
    __syncthreads();
    s16x8 af[4], bf[4];
#pragma unroll
    for (int i = 0; i < 4; i++)
      af[i] = *(const s16x8*)(As + (wm + i * 16 + l16) * 32 + quad * 8);
#pragma unroll
    for (int n = 0; n < 4; n++)
      bf[n] = *(const s16x8*)(Bs + (wn + n * 16 + l16) * 32 + quad * 8);
#pragma unroll
    for (int i = 0; i < 4; i++)
#pragma unroll
      for (int n = 0; n < 4; n++)
        acc[i][n] = __builtin_amdgcn_mfma_f32_16x16x32_bf16(af[i], bf[n], acc[i][n], 0, 0, 0);
    __syncthreads();
  }

  const int sec = n0 / 768;  // 0=q, 1=k, 2=v (uniform per block)
  if (sec < 2) {
    ushort* dst = sec == 0 ? Qb : Kb;
#pragma unroll
    for (int i = 0; i < 4; i++) {
      int row0 = m0 + wm + i * 16 + quad * 4;
#pragma unroll
      for (int nt = 0; nt < 4; nt++) {
        int col = n0 + wn + nt * 16 + l16;
        int nn = col - sec * 768;
        int h = nn >> 6, d = nn & 63;
        int ip = (d >> 1) & 31;
        float sgn = (d & 1) ? 1.f : -1.f;
#pragma unroll
        for (int r = 0; r < 4; r++) {
          int rrow = row0 + r;
          int t = rrow & (T_ - 1), b = rrow >> 11;
          float v = acc[i][nt][r];
          float partner = __shfl_xor(v, 1);
          float2 cs = cs2[t * 32 + ip];
          float out = fmaf(v, cs.x, sgn * partner * cs.y);
          dst[((size_t)(b * H_ + h) * T_ + t) * DH + d] = f2b(out);
        }
      }
    }
  } else {
#pragma unroll
    for (int i = 0; i < 4; i++) {
      int row0 = m0 + wm + i * 16 + quad * 4;
      int t0 = row0 & (T_ - 1), b = row0 >> 11;  // 4 rows share b (aligned)
#pragma unroll
      for (int nt = 0; nt < 4; nt++) {
        int col = n0 + wn + nt * 16 + l16;
        int nn = col - 1536;
        int h = nn >> 6, d = nn & 63;
        ushort4 pk;
        pk.x = f2b(acc[i][nt][0]); pk.y = f2b(acc[i][nt][1]);
        pk.z = f2b(acc[i][nt][2]); pk.w = f2b(acc[i][nt][3]);
        *(ushort4*)(Vt + ((size_t)(b * H_ + h) * DH + d) * T_ + t0) = pk;
      }
    }
  }
}

// ---------------- output GEMM: 128x64 tiles (768 blocks = 3/CU) ----------------
__global__ __launch_bounds__(256) void gemm_out(
    const ushort* __restrict__ A, const ushort* __restrict__ Bw, float* __restrict__ C) {
  const int K = 768, N = 768;
  __shared__ ushort As[128 * 32];
  __shared__ ushort Bs[64 * 32];
  const int m0 = blockIdx.y * 128, n0 = blockIdx.x * 64;
  const int tid = threadIdx.x;
  const int wave = tid >> 6, lane = tid & 63;
  const int wm = wave * 32;
  const int quad = lane >> 4, l16 = lane & 15;
  const int tr = tid >> 2, tc = (tid & 3) * 8;

  f32x4 acc[2][4] = {};

  const ushort* ga = A + (size_t)(m0 + tr) * K + tc;
  const ushort* gb = Bw + (size_t)(n0 + tr) * K + tc;

  for (int k0 = 0; k0 < K; k0 += 32) {
    __builtin_amdgcn_global_load_lds((gas1_t)(ga + k0), (las3_t)(As + tid * 8), 16, 0, 0);
    __builtin_amdgcn_global_load_lds((gas1_t)(ga + (size_t)64 * K + k0), (las3_t)(As + 2048 + tid * 8), 16, 0, 0);
    __builtin_amdgcn_global_load_lds((gas1_t)(gb + k0), (las3_t)(Bs + tid * 8), 16, 0, 0);
    __syncthreads();
    s16x8 af[2], bf[4];
#pragma unroll
    for (int i = 0; i < 2; i++)
      af[i] = *(const s16x8*)(As + (wm + i * 16 + l16) * 32 + quad * 8);
#pragma unroll
    for (int n = 0; n < 4; n++)
      bf[n] = *(const s16x8*)(Bs + (n * 16 + l16) * 32 + quad * 8);
#pragma unroll
    for (int i = 0; i < 2; i++)
#pragma unroll
      for (int n = 0; n < 4; n++)
        acc[i][n] = __builtin_amdgcn_mfma_f32_16x16x32_bf16(af[i], bf[n], acc[i][n], 0, 0, 0);
    __syncthreads();
  }

#pragma unroll
  for (int i = 0; i < 2; i++) {
    int row = m0 + wm + i * 16 + quad * 4;
#pragma unroll
    for (int n = 0; n < 4; n++) {
      int col = n0 + n * 16 + l16;
#pragma unroll
      for (int r = 0; r < 4; r++)
        C[(size_t)(row + r) * N + col] = acc[i][n][r];
    }
  }
}

// ---------------- causal flash attention v6: dbuf LDS staging ----------------
// grid (48 bh, 16 qt128-desc). 4 waves; wave w owns 32 q rows (two 16-row
// m-frags). K/V double-buffered in LDS: one barrier per tile, prefetch of
// tile c+1 issued immediately after the barrier -> vmcnt drain overlapped
// with a full compute phase. P buffer shared across m (LDS in-order per wave).
#define EXP2SCALE 0.18033688f   /* 0.125 * log2(e) */
#define EXP2OFF  17.312340f     /* 12 * log2(e) */
__global__ __launch_bounds__(256, 3) void attn(const ushort* __restrict__ Qb, const ushort* __restrict__ Kb,
                                               const ushort* __restrict__ Vt, ushort* __restrict__ Ob) {
  const int bh = blockIdx.x;
  const int qt = 15 - blockIdx.y;  // biggest tiles dispatch first
  const int tid = threadIdx.x, wave = tid >> 6, lane = tid & 63;
  const int quad = lane >> 4, l16 = lane & 15;
  const int b = bh / H_, h = bh % H_;
  const ushort* Qp = Qb + (size_t)bh * T_ * DH;
  const ushort* Kp = Kb + (size_t)bh * T_ * DH;
  const ushort* Vp = Vt + (size_t)bh * DH * T_;

  __shared__ ushort Ks[2][64 * 64];
  __shared__ ushort Vs[2][64 * 64];
  __shared__ ushort P[4][16][72];   // per wave, shared across m-frags

  const int qbase0 = qt * 128 + wave * 32;

  s16x8 aq[2][2];
#pragma unroll
  for (int m = 0; m < 2; m++) {
    const ushort* qp = Qp + (size_t)(qbase0 + m * 16 + l16) * DH + quad * 8;
    aq[m][0] = *(const s16x8*)qp;
    aq[m][1] = *(const s16x8*)(qp + 32);
  }
  f32x4 o[2][4] = {};
  float rsum[2][4] = {{0.f, 0.f, 0.f, 0.f}, {0.f, 0.f, 0.f, 0.f}};

  const int ntile = 2 * qt + 2;
  const int srow = tid >> 3;                   // 0..31
  const int scbK = (tid & 7) ^ (srow & 7);     // swizzled source colblock
  const int swz = (l16 & 7);

  // issue stage of tile 0 into buffer 0
  {
    const int kv0 = 0;
    __builtin_amdgcn_global_load_lds((gas1_t)(Kp + (size_t)(kv0 + srow) * DH + scbK * 8),
                                     (las3_t)(Ks[0] + tid * 8), 16, 0, 0);
    __builtin_amdgcn_global_load_lds((gas1_t)(Kp + (size_t)(kv0 + srow + 32) * DH + scbK * 8),
                                     (las3_t)(Ks[0] + 2048 + tid * 8), 16, 0, 0);
    __builtin_amdgcn_global_load_lds((gas1_t)(Vp + (size_t)srow * T_ + kv0 + scbK * 8),
                                     (las3_t)(Vs[0] + tid * 8), 16, 0, 0);
    __builtin_amdgcn_global_load_lds((gas1_t)(Vp + (size_t)(srow + 32) * T_ + kv0 + scbK * 8),
                                     (las3_t)(Vs[0] + 2048 + tid * 8), 16, 0, 0);
  }

  for (int c = 0; c < ntile; c++) {
    const int kv0 = c * 64;
    const int cur = c & 1;
    __syncthreads();  // drains own vmcnt -> buf[cur] staged & visible
    if (c + 1 < ntile) {
      const int kv1 = kv0 + 64, nxt = cur ^ 1;
      __builtin_amdgcn_global_load_lds((gas1_t)(Kp + (size_t)(kv1 + srow) * DH + scbK * 8),
                                       (las3_t)(Ks[nxt] + tid * 8), 16, 0, 0);
      __builtin_amdgcn_global_load_lds((gas1_t)(Kp + (size_t)(kv1 + srow + 32) * DH + scbK * 8),
                                       (las3_t)(Ks[nxt] + 2048 + tid * 8), 16, 0, 0);
      __builtin_amdgcn_global_load_lds((gas1_t)(Vp + (size_t)srow * T_ + kv1 + scbK * 8),
                                       (las3_t)(Vs[nxt] + tid * 8), 16, 0, 0);
      __builtin_amdgcn_global_load_lds((gas1_t)(Vp + (size_t)(srow + 32) * T_ + kv1 + scbK * 8),
                                       (las3_t)(Vs[nxt] + 2048 + tid * 8), 16, 0, 0);
    }

    s16x8 kf[4][2];
#pragma unroll
    for (int nt = 0; nt < 4; nt++) {
      const ushort* kr = Ks[cur] + (nt * 16 + l16) * 64;
      kf[nt][0] = *(const s16x8*)(kr + ((quad ^ swz) * 8));
      kf[nt][1] = *(const s16x8*)(kr + (((4 + quad) ^ swz) * 8));
    }
    s16x8 bv[4][2];
#pragma unroll
    for (int dt = 0; dt < 4; dt++) {
      const ushort* vr = Vs[cur] + (dt * 16 + l16) * 64;
      bv[dt][0] = *(const s16x8*)(vr + ((quad ^ swz) * 8));
      bv[dt][1] = *(const s16x8*)(vr + (((4 + quad) ^ swz) * 8));
    }

#pragma unroll
    for (int m = 0; m < 2; m++) {
      const int qb = qbase0 + m * 16;
      if (kv0 > qb + 15) continue;  // fully masked frag (wave-uniform)
      f32x4 s[4] = {};
#pragma unroll
      for (int nt = 0; nt < 4; nt++) {
        s[nt] = __builtin_amdgcn_mfma_f32_16x16x32_bf16(aq[m][0], kf[nt][0], s[nt], 0, 0, 0);
        s[nt] = __builtin_amdgcn_mfma_f32_16x16x32_bf16(aq[m][1], kf[nt][1], s[nt], 0, 0, 0);
      }
      if (kv0 + 63 <= qb) {  // fully unmasked
#pragma unroll
        for (int nt = 0; nt < 4; nt++)
#pragma unroll
          for (int r = 0; r < 4; r++) {
            float p = __builtin_amdgcn_exp2f(fmaf(s[nt][r], EXP2SCALE, -EXP2OFF));
            rsum[m][r] += p;
            P[wave][quad * 4 + r][nt * 16 + l16] = f2b(p);
          }
      } else {  // diagonal tile
#pragma unroll
        for (int nt = 0; nt < 4; nt++) {
          int kv = kv0 + nt * 16 + l16;
#pragma unroll
          for (int r = 0; r < 4; r++) {
            int qi = qb + quad * 4 + r;
            float p = (kv <= qi) ? __builtin_amdgcn_exp2f(fmaf(s[nt][r], EXP2SCALE, -EXP2OFF)) : 0.f;
            rsum[m][r] += p;
            P[wave][quad * 4 + r][nt * 16 + l16] = f2b(p);
          }
        }
      }
      s16x8 ap0 = *(const s16x8*)&P[wave][l16][quad * 8];
      s16x8 ap1 = *(const s16x8*)&P[wave][l16][32 + quad * 8];
#pragma unroll
      for (int dt = 0; dt < 4; dt++) {
        o[m][dt] = __builtin_amdgcn_mfma_f32_16x16x32_bf16(ap0, bv[dt][0], o[m][dt], 0, 0, 0);
        o[m][dt] = __builtin_amdgcn_mfma_f32_16x16x32_bf16(ap1, bv[dt][1], o[m][dt], 0, 0, 0);
      }
    }
  }
#pragma unroll
  for (int off = 1; off < 16; off <<= 1)
#pragma unroll
    for (int m = 0; m < 2; m++)
#pragma unroll
      for (int r = 0; r < 4; r++)
        rsum[m][r] += __shfl_xor(rsum[m][r], off);
#pragma unroll
  for (int m = 0; m < 2; m++)
#pragma unroll
    for (int dt = 0; dt < 4; dt++)
#pragma unroll
      for (int r = 0; r < 4; r++) {
        int q = qbase0 + m * 16 + quad * 4 + r;
        Ob[(size_t)(b * T_ + q) * DM + h * 64 + dt * 16 + l16] = f2b(o[m][dt][r] / rsum[m][r]);
      }
}

extern "C" void kernel_launch(void* const* d_in, const int* in_sizes, int n_in,
                              void* d_out, int out_size, void* d_ws, size_t ws_size,
                              hipStream_t stream) {
  const float* x = (const float*)d_in[0];
  const float* rc = (const float*)d_in[1];
  const float* rs = (const float*)d_in[2];
  const float* wq = (const float*)d_in[3];
  const float* wk = (const float*)d_in[4];
  const float* wv = (const float*)d_in[5];
  const float* wo = (const float*)d_in[6];

  char* ws = (char*)d_ws;
  ushort* xb   = (ushort*)(ws);                 // 12,582,912
  ushort* wqkv = (ushort*)(ws + 12582912);      //  3,538,944
  ushort* wob  = (ushort*)(ws + 16121856);      //  1,179,648
  float2* cs2  = (float2*)(ws + 17301504);      //    524,288
  ushort* Qb   = (ushort*)(ws + 17825792);      // 12,582,912
  ushort* Kb   = (ushort*)(ws + 30408704);      // 12,582,912
  ushort* Vt   = (ushort*)(ws + 42991616);      // 12,582,912
  ushort* Ob   = (ushort*)(ws + 55574528);      // 12,582,912 (ends ~68.2MB)

  cvt_bf16<<<6144, 256, 0, stream>>>(x, xb, 8192 * 768 / 4);
  cvt_w<<<2304, 256, 0, stream>>>(wq, wk, wv, wo, wqkv, wob);
  pack_cs<<<256, 256, 0, stream>>>(rc, rs, cs2, T_ * 32);

  gemm_qkv<<<dim3(18, 64), 256, 0, stream>>>(xb, wqkv, cs2, Qb, Kb, Vt);

  attn<<<dim3(48, 16), 256, 0, stream>>>(Qb, Kb, Vt, Ob);

  gemm_out<<<dim3(12, 64), 256, 0, stream>>>(Ob, wob, (float*)d_out);
}

// Round 8
// 230.120 us; speedup vs baseline: 2.1378x; 1.0053x over previous
//
#include <hip/hip_runtime.h>
#include <hip/hip_bf16.h>
#include <math.h>

#define B_ 4
#define T_ 2048
#define DM 768
#define H_ 12
#define DH 64

typedef __attribute__((ext_vector_type(4))) float f32x4;
typedef __attribute__((ext_vector_type(8))) short s16x8;

typedef const __attribute__((address_space(1))) void* gas1_t;
typedef __attribute__((address_space(3))) void* las3_t;

__device__ __forceinline__ ushort f2b(float f) {
  union { float f; unsigned u; } v; v.f = f;
  unsigned u = v.u;
  u += 0x7fffu + ((u >> 16) & 1u);
  return (ushort)(u >> 16);
}
__device__ __forceinline__ float b2f(ushort b) {
  union { unsigned u; float f; } v; v.u = ((unsigned)b) << 16;
  return v.f;
}

// ---------------- fp32 -> bf16 conversion, 4 elems/thread ----------------
__global__ void cvt_bf16(const float* __restrict__ src, ushort* __restrict__ dst, int n4) {
  int i = blockIdx.x * blockDim.x + threadIdx.x;
  if (i >= n4) return;
  float4 v = ((const float4*)src)[i];
  ushort4 o;
  o.x = f2b(v.x); o.y = f2b(v.y); o.z = f2b(v.z); o.w = f2b(v.w);
  ((ushort4*)dst)[i] = o;
}

// fused conversion of the 4 weight matrices (each 768*768; n4 each = 147456)
__global__ void cvt_w(const float* __restrict__ wq, const float* __restrict__ wk,
                      const float* __restrict__ wv, const float* __restrict__ wo,
                      ushort* __restrict__ wqkv, ushort* __restrict__ wob) {
  int i = blockIdx.x * blockDim.x + threadIdx.x;  // 4*147456 threads
  int which = i / 147456, j = i - which * 147456;
  const float* src = which == 0 ? wq : which == 1 ? wk : which == 2 ? wv : wo;
  ushort* dst = which < 3 ? wqkv + (size_t)which * 589824 : wob;
  float4 v = ((const float4*)src)[j];
  ushort4 o;
  o.x = f2b(v.x); o.y = f2b(v.y); o.z = f2b(v.z); o.w = f2b(v.w);
  ((ushort4*)dst)[j] = o;
}

// pack cos/sin tables into float2 [t][i]
__global__ void pack_cs(const float* __restrict__ cs, const float* __restrict__ sn,
                        float2* __restrict__ cs2, int n) {
  int i = blockIdx.x * blockDim.x + threadIdx.x;
  if (i < n) cs2[i] = make_float2(cs[i], sn[i]);
}

// ---------------- QKV GEMM with fused RoPE + scatter epilogue ----------------
// LDS staging XOR-swizzled with (row>>1)&3 so the 8-lane scheduling subgroups
// of ds_read_b128 hit the 8 distinct 16B bank-groups (row stride 64B gives
// one group bit from row&1, two from colblock).
__global__ __launch_bounds__(256) void gemm_qkv(
    const ushort* __restrict__ A, const ushort* __restrict__ Bw,
    const float2* __restrict__ cs2,
    ushort* __restrict__ Qb, ushort* __restrict__ Kb, ushort* __restrict__ Vt) {
  const int K = 768;
  __shared__ ushort As[128 * 32];
  __shared__ ushort Bs[128 * 32];
  const int m0 = blockIdx.y * 128, n0 = blockIdx.x * 128;
  const int tid = threadIdx.x;
  const int wave = tid >> 6, lane = tid & 63;
  const int wm = (wave >> 1) * 64, wn = (wave & 1) * 64;
  const int quad = lane >> 4, l16 = lane & 15;
  const int tr = tid >> 2;                        // staging row 0..63
  const int scb = (tid & 3) ^ ((tr >> 1) & 3);    // swizzled source colblock
  const int fsw = (l16 >> 1) & 3;                 // frag-read swizzle term

  f32x4 acc[4][4] = {};

  const ushort* ga = A + (size_t)(m0 + tr) * K + scb * 8;
  const ushort* gb = Bw + (size_t)(n0 + tr) * K + scb * 8;

  for (int k0 = 0; k0 < K; k0 += 32) {
    __builtin_amdgcn_global_load_lds((gas1_t)(ga + k0), (las3_t)(As + tid * 8), 16, 0, 0);
    __builtin_amdgcn_global_load_lds((gas1_t)(ga + (size_t)64 * K + k0), (las3_t)(As + 2048 + tid * 8), 16, 0, 0);
    __builtin_amdgcn_global_load_lds((gas1_t)(gb + k0), (las3_t)(Bs + tid * 8), 16, 0, 0);
    __builtin_amdgcn_global_load_lds((gas1_t)(gb + (size_t)64 * K + k0), (las3_t)(Bs + 2048 + tid * 8), 16, 0, 0);
    __syncthreads();
    s16x8 af[4], bf[4];
#pragma unroll
    for (int i = 0; i < 4; i++)
      af[i] = *(const s16x8*)(As + (wm + i * 16 + l16) * 32 + (quad ^ fsw) * 8);
#pragma unroll
    for (int n = 0; n < 4; n++)
      bf[n] = *(const s16x8*)(Bs + (wn + n * 16 + l16) * 32 + (quad ^ fsw) * 8);
#pragma unroll
    for (int i = 0; i < 4; i++)
#pragma unroll
      for (int n = 0; n < 4; n++)
        acc[i][n] = __builtin_amdgcn_mfma_f32_16x16x32_bf16(af[i], bf[n], acc[i][n], 0, 0, 0);
    __syncthreads();
  }

  const int sec = n0 / 768;  // 0=q, 1=k, 2=v (uniform per block)
  if (sec < 2) {
    ushort* dst = sec == 0 ? Qb : Kb;
#pragma unroll
    for (int i = 0; i < 4; i++) {
      int row0 = m0 + wm + i * 16 + quad * 4;
#pragma unroll
      for (int nt = 0; nt < 4; nt++) {
        int col = n0 + wn + nt * 16 + l16;
        int nn = col - sec * 768;
        int h = nn >> 6, d = nn & 63;
        int ip = (d >> 1) & 31;
        float sgn = (d & 1) ? 1.f : -1.f;
#pragma unroll
        for (int r = 0; r < 4; r++) {
          int rrow = row0 + r;
          int t = rrow & (T_ - 1), bb = rrow >> 11;
          float v = acc[i][nt][r];
          float partner = __shfl_xor(v, 1);
          float2 cs = cs2[t * 32 + ip];
          float out = fmaf(v, cs.x, sgn * partner * cs.y);
          dst[((size_t)(bb * H_ + h) * T_ + t) * DH + d] = f2b(out);
        }
      }
    }
  } else {
#pragma unroll
    for (int i = 0; i < 4; i++) {
      int row0 = m0 + wm + i * 16 + quad * 4;
      int t0 = row0 & (T_ - 1), b = row0 >> 11;  // 4 rows share b (aligned)
#pragma unroll
      for (int nt = 0; nt < 4; nt++) {
        int col = n0 + wn + nt * 16 + l16;
        int nn = col - 1536;
        int h = nn >> 6, d = nn & 63;
        ushort4 pk;
        pk.x = f2b(acc[i][nt][0]); pk.y = f2b(acc[i][nt][1]);
        pk.z = f2b(acc[i][nt][2]); pk.w = f2b(acc[i][nt][3]);
        *(ushort4*)(Vt + ((size_t)(b * H_ + h) * DH + d) * T_ + t0) = pk;
      }
    }
  }
}

// ---------------- output GEMM: 128x64 tiles, swizzled LDS ----------------
__global__ __launch_bounds__(256) void gemm_out(
    const ushort* __restrict__ A, const ushort* __restrict__ Bw, float* __restrict__ C) {
  const int K = 768, N = 768;
  __shared__ ushort As[128 * 32];
  __shared__ ushort Bs[64 * 32];
  const int m0 = blockIdx.y * 128, n0 = blockIdx.x * 64;
  const int tid = threadIdx.x;
  const int wave = tid >> 6, lane = tid & 63;
  const int wm = wave * 32;
  const int quad = lane >> 4, l16 = lane & 15;
  const int tr = tid >> 2;
  const int scb = (tid & 3) ^ ((tr >> 1) & 3);
  const int fsw = (l16 >> 1) & 3;

  f32x4 acc[2][4] = {};

  const ushort* ga = A + (size_t)(m0 + tr) * K + scb * 8;
  const ushort* gb = Bw + (size_t)(n0 + tr) * K + scb * 8;

  for (int k0 = 0; k0 < K; k0 += 32) {
    __builtin_amdgcn_global_load_lds((gas1_t)(ga + k0), (las3_t)(As + tid * 8), 16, 0, 0);
    __builtin_amdgcn_global_load_lds((gas1_t)(ga + (size_t)64 * K + k0), (las3_t)(As + 2048 + tid * 8), 16, 0, 0);
    __builtin_amdgcn_global_load_lds((gas1_t)(gb + k0), (las3_t)(Bs + tid * 8), 16, 0, 0);
    __syncthreads();
    s16x8 af[2], bf[4];
#pragma unroll
    for (int i = 0; i < 2; i++)
      af[i] = *(const s16x8*)(As + (wm + i * 16 + l16) * 32 + (quad ^ fsw) * 8);
#pragma unroll
    for (int n = 0; n < 4; n++)
      bf[n] = *(const s16x8*)(Bs + (n * 16 + l16) * 32 + (quad ^ fsw) * 8);
#pragma unroll
    for (int i = 0; i < 2; i++)
#pragma unroll
      for (int n = 0; n < 4; n++)
        acc[i][n] = __builtin_amdgcn_mfma_f32_16x16x32_bf16(af[i], bf[n], acc[i][n], 0, 0, 0);
    __syncthreads();
  }

#pragma unroll
  for (int i = 0; i < 2; i++) {
    int row = m0 + wm + i * 16 + quad * 4;
#pragma unroll
    for (int n = 0; n < 4; n++) {
      int col = n0 + n * 16 + l16;
#pragma unroll
      for (int r = 0; r < 4; r++)
        C[(size_t)(row + r) * N + col] = acc[i][n][r];
    }
  }
}

// ---------------- causal flash attention v6: dbuf LDS staging ----------------
#define EXP2SCALE 0.18033688f   /* 0.125 * log2(e) */
#define EXP2OFF  17.312340f     /* 12 * log2(e) */
__global__ __launch_bounds__(256, 3) void attn(const ushort* __restrict__ Qb, const ushort* __restrict__ Kb,
                                               const ushort* __restrict__ Vt, ushort* __restrict__ Ob) {
  const int bh = blockIdx.x;
  const int qt = 15 - blockIdx.y;  // biggest tiles dispatch first
  const int tid = threadIdx.x, wave = tid >> 6, lane = tid & 63;
  const int quad = lane >> 4, l16 = lane & 15;
  const int b = bh / H_, h = bh % H_;
  const ushort* Qp = Qb + (size_t)bh * T_ * DH;
  const ushort* Kp = Kb + (size_t)bh * T_ * DH;
  const ushort* Vp = Vt + (size_t)bh * DH * T_;

  __shared__ ushort Ks[2][64 * 64];
  __shared__ ushort Vs[2][64 * 64];
  __shared__ ushort P[4][16][72];   // per wave, shared across m-frags

  const int qbase0 = qt * 128 + wave * 32;

  s16x8 aq[2][2];
#pragma unroll
  for (int m = 0; m < 2; m++) {
    const ushort* qp = Qp + (size_t)(qbase0 + m * 16 + l16) * DH + quad * 8;
    aq[m][0] = *(const s16x8*)qp;
    aq[m][1] = *(const s16x8*)(qp + 32);
  }
  f32x4 o[2][4] = {};
  float rsum[2][4] = {{0.f, 0.f, 0.f, 0.f}, {0.f, 0.f, 0.f, 0.f}};

  const int ntile = 2 * qt + 2;
  const int srow = tid >> 3;                   // 0..31
  const int scbK = (tid & 7) ^ (srow & 7);     // swizzled source colblock
  const int swz = (l16 & 7);

  {
    const int kv0 = 0;
    __builtin_amdgcn_global_load_lds((gas1_t)(Kp + (size_t)(kv0 + srow) * DH + scbK * 8),
                                     (las3_t)(Ks[0] + tid * 8), 16, 0, 0);
    __builtin_amdgcn_global_load_lds((gas1_t)(Kp + (size_t)(kv0 + srow + 32) * DH + scbK * 8),
                                     (las3_t)(Ks[0] + 2048 + tid * 8), 16, 0, 0);
    __builtin_amdgcn_global_load_lds((gas1_t)(Vp + (size_t)srow * T_ + kv0 + scbK * 8),
                                     (las3_t)(Vs[0] + tid * 8), 16, 0, 0);
    __builtin_amdgcn_global_load_lds((gas1_t)(Vp + (size_t)(srow + 32) * T_ + kv0 + scbK * 8),
                                     (las3_t)(Vs[0] + 2048 + tid * 8), 16, 0, 0);
  }

  for (int c = 0; c < ntile; c++) {
    const int kv0 = c * 64;
    const int cur = c & 1;
    __syncthreads();  // drains own vmcnt -> buf[cur] staged & visible
    if (c + 1 < ntile) {
      const int kv1 = kv0 + 64, nxt = cur ^ 1;
      __builtin_amdgcn_global_load_lds((gas1_t)(Kp + (size_t)(kv1 + srow) * DH + scbK * 8),
                                       (las3_t)(Ks[nxt] + tid * 8), 16, 0, 0);
      __builtin_amdgcn_global_load_lds((gas1_t)(Kp + (size_t)(kv1 + srow + 32) * DH + scbK * 8),
                                       (las3_t)(Ks[nxt] + 2048 + tid * 8), 16, 0, 0);
      __builtin_amdgcn_global_load_lds((gas1_t)(Vp + (size_t)srow * T_ + kv1 + scbK * 8),
                                       (las3_t)(Vs[nxt] + tid * 8), 16, 0, 0);
      __builtin_amdgcn_global_load_lds((gas1_t)(Vp + (size_t)(srow + 32) * T_ + kv1 + scbK * 8),
                                       (las3_t)(Vs[nxt] + 2048 + tid * 8), 16, 0, 0);
    }

    s16x8 kf[4][2];
#pragma unroll
    for (int nt = 0; nt < 4; nt++) {
      const ushort* kr = Ks[cur] + (nt * 16 + l16) * 64;
      kf[nt][0] = *(const s16x8*)(kr + ((quad ^ swz) * 8));
      kf[nt][1] = *(const s16x8*)(kr + (((4 + quad) ^ swz) * 8));
    }
    s16x8 bv[4][2];
#pragma unroll
    for (int dt = 0; dt < 4; dt++) {
      const ushort* vr = Vs[cur] + (dt * 16 + l16) * 64;
      bv[dt][0] = *(const s16x8*)(vr + ((quad ^ swz) * 8));
      bv[dt][1] = *(const s16x8*)(vr + (((4 + quad) ^ swz) * 8));
    }

#pragma unroll
    for (int m = 0; m < 2; m++) {
      const int qb = qbase0 + m * 16;
      if (kv0 > qb + 15) continue;  // fully masked frag (wave-uniform)
      f32x4 s[4] = {};
#pragma unroll
      for (int nt = 0; nt < 4; nt++) {
        s[nt] = __builtin_amdgcn_mfma_f32_16x16x32_bf16(aq[m][0], kf[nt][0], s[nt], 0, 0, 0);
        s[nt] = __builtin_amdgcn_mfma_f32_16x16x32_bf16(aq[m][1], kf[nt][1], s[nt], 0, 0, 0);
      }
      if (kv0 + 63 <= qb) {  // fully unmasked
#pragma unroll
        for (int nt = 0; nt < 4; nt++)
#pragma unroll
          for (int r = 0; r < 4; r++) {
            float p = __builtin_amdgcn_exp2f(fmaf(s[nt][r], EXP2SCALE, -EXP2OFF));
            rsum[m][r] += p;
            P[wave][quad * 4 + r][nt * 16 + l16] = f2b(p);
          }
      } else {  // diagonal tile
#pragma unroll
        for (int nt = 0; nt < 4; nt++) {
          int kv = kv0 + nt * 16 + l16;
#pragma unroll
          for (int r = 0; r < 4; r++) {
            int qi = qb + quad * 4 + r;
            float p = (kv <= qi) ? __builtin_amdgcn_exp2f(fmaf(s[nt][r], EXP2SCALE, -EXP2OFF)) : 0.f;
            rsum[m][r] += p;
            P[wave][quad * 4 + r][nt * 16 + l16] = f2b(p);
          }
        }
      }
      s16x8 ap0 = *(const s16x8*)&P[wave][l16][quad * 8];
      s16x8 ap1 = *(const s16x8*)&P[wave][l16][32 + quad * 8];
#pragma unroll
      for (int dt = 0; dt < 4; dt++) {
        o[m][dt] = __builtin_amdgcn_mfma_f32_16x16x32_bf16(ap0, bv[dt][0], o[m][dt], 0, 0, 0);
        o[m][dt] = __builtin_amdgcn_mfma_f32_16x16x32_bf16(ap1, bv[dt][1], o[m][dt], 0, 0, 0);
      }
    }
  }
#pragma unroll
  for (int off = 1; off < 16; off <<= 1)
#pragma unroll
    for (int m = 0; m < 2; m++)
#pragma unroll
      for (int r = 0; r < 4; r++)
        rsum[m][r] += __shfl_xor(rsum[m][r], off);
#pragma unroll
  for (int m = 0; m < 2; m++)
#pragma unroll
    for (int dt = 0; dt < 4; dt++)
#pragma unroll
      for (int r = 0; r < 4; r++) {
        int q = qbase0 + m * 16 + quad * 4 + r;
        Ob[(size_t)(b * T_ + q) * DM + h * 64 + dt * 16 + l16] = f2b(o[m][dt][r] / rsum[m][r]);
      }
}

extern "C" void kernel_launch(void* const* d_in, const int* in_sizes, int n_in,
                              void* d_out, int out_size, void* d_ws, size_t ws_size,
                              hipStream_t stream) {
  const float* x = (const float*)d_in[0];
  const float* rc = (const float*)d_in[1];
  const float* rs = (const float*)d_in[2];
  const float* wq = (const float*)d_in[3];
  const float* wk = (const float*)d_in[4];
  const float* wv = (const float*)d_in[5];
  const float* wo = (const float*)d_in[6];

  char* ws = (char*)d_ws;
  ushort* xb   = (ushort*)(ws);                 // 12,582,912
  ushort* wqkv = (ushort*)(ws + 12582912);      //  3,538,944
  ushort* wob  = (ushort*)(ws + 16121856);      //  1,179,648
  float2* cs2  = (float2*)(ws + 17301504);      //    524,288
  ushort* Qb   = (ushort*)(ws + 17825792);      // 12,582,912
  ushort* Kb   = (ushort*)(ws + 30408704);      // 12,582,912
  ushort* Vt   = (ushort*)(ws + 42991616);      // 12,582,912
  ushort* Ob   = (ushort*)(ws + 55574528);      // 12,582,912 (ends ~68.2MB)

  cvt_bf16<<<6144, 256, 0, stream>>>(x, xb, 8192 * 768 / 4);
  cvt_w<<<2304, 256, 0, stream>>>(wq, wk, wv, wo, wqkv, wob);
  pack_cs<<<256, 256, 0, stream>>>(rc, rs, cs2, T_ * 32);

  gemm_qkv<<<dim3(18, 64), 256, 0, stream>>>(xb, wqkv, cs2, Qb, Kb, Vt);

  attn<<<dim3(48, 16), 256, 0, stream>>>(Qb, Kb, Vt, Ob);

  gemm_out<<<dim3(12, 64), 256, 0, stream>>>(Ob, wob, (float*)d_out);
}